// Round 22
// baseline (56.390 us; speedup 1.0000x reference)
//
#include <hip/hip_runtime.h>
#include <stdint.h>

// SSIM fused kernel v22, MI355X (gfx950).
// v21 post-mortem: WIN (62.5->58.5us rocprof). VALU 75% = lone loaded pipe;
// math is >=80% of the instruction stream, fully pk-packed -> op cuts
// exhausted. Last observable: occupancy 51% vs 62.5% static ceiling at
// 5 blocks/CU, and achieved occupancy now TRACKS allowed blocks (0.82x).
// v22 = v21 with __launch_bounds__(256,6): LDS 24.06KB x 6 = 144.4 <= 160KB,
// VGPR 40 << cap 84. One more resident block smooths block-drain bubbles.
// Pre-commitment: if >= 58us rocprof, declare structural floor.

#define HH 512
#define WW 512
#define PLANES 48
#define TW 64
#define TH 16
#define RR 5
#define KK 11
#define HALO_W 74                  // halo cols c=0..73, global x = x0-5+c
#define RBW 74                     // rbA2/rbB2 row stride (float2)
#define RCW 76                     // rbC row stride (float, 16B row align)
#define NBLOCKS (PLANES * (WW / TW) * (HH / TH))  // 12288
#define NTHREADS 256
#define NITEMS1 (HALO_W * 2)      // 148 pass-1 items (col, 8-row group)
#define TOTAL_ELEMS (PLANES * HH * WW)

typedef float float2v __attribute__((ext_vector_type(2)));

constexpr float G_[KK] = {
    1.4867195147342977e-06f, 1.3383022576488537e-04f, 4.4318484119380075e-03f,
    5.3990966513188063e-02f, 2.4197072451914337e-01f, 3.9894228040143270e-01f,
    2.4197072451914337e-01f, 5.3990966513188063e-02f, 4.4318484119380075e-03f,
    1.3383022576488537e-04f, 1.4867195147342977e-06f};

__global__ __launch_bounds__(NTHREADS, 6) void ssim_tile_kernel(
    const float* __restrict__ pred, const float* __restrict__ targ,
    float* __restrict__ partial) {
  __shared__ __align__(16) float2v rbA2[TH][RBW];   // 9.25 KB (p, t) f32
  __shared__ __align__(16) float2v rbB2[TH][RBW];   // 9.25 KB (pp, tt) f32
  __shared__ __align__(16) float rbC[TH][RCW];      // 4.75 KB pt f32
  __shared__ float wsums[4];

  const int tid = threadIdx.x;
  const int bid = blockIdx.x;
  const int plane = bid >> 8;
  const int tile = bid & 255;
  const int x0 = (tile & 7) * TW;
  const int y0 = (tile >> 3) * TH;
  const float* pp = pred + (size_t)plane * (HH * WW);
  const float* tp = targ + (size_t)plane * (HH * WW);

  const bool interior = (x0 >= 64) && (x0 <= 384) && (y0 >= 16) && (y0 <= 480);

  // ---- Pass 1: fused global-load + VERTICAL conv, 8 outputs/item ----
  if (tid < NITEMS1) {
    const int c = (tid < HALO_W) ? tid : (tid - HALO_W);  // halo col 0..73
    const int g = (tid < HALO_W) ? 0 : 1;                  // row group
    const int yb = g * 8;            // output rows yb..yb+7; window yb..yb+17
    const int gx = x0 - RR + c;

    float pv[18], tv[18];
    if (interior) {
      const float* pc = pp + (size_t)(y0 - RR + yb) * WW + gx;
      const float* tc = tp + (size_t)(y0 - RR + yb) * WW + gx;
#pragma unroll
      for (int q = 0; q < 18; ++q) {
        pv[q] = pc[(size_t)q * WW];   // coalesced: consecutive c = consec gx
        tv[q] = tc[(size_t)q * WW];
      }
    } else {
      const bool xok = (gx >= 0) && (gx < WW);
#pragma unroll
      for (int q = 0; q < 18; ++q) {
        const int gy = y0 - RR + yb + q;
        const bool ok = xok && (gy >= 0) && (gy < HH);
        const int o = gy * WW + gx;
        pv[q] = ok ? pp[o] : 0.f;
        tv[q] = ok ? tp[o] : 0.f;
      }
    }

    // Scatter: window row q (0..17) feeds outputs j in [q-10, q] ∩ [0,7]
    // with weight G_[q-j].
    float2v s01[8] = {{0,0},{0,0},{0,0},{0,0},{0,0},{0,0},{0,0},{0,0}};
    float2v s23[8] = {{0,0},{0,0},{0,0},{0,0},{0,0},{0,0},{0,0},{0,0}};
    float s4[8] = {0,0,0,0,0,0,0,0};
#pragma unroll
    for (int q = 0; q < 18; ++q) {
      const float a = pv[q];
      const float b = tv[q];
      const float2v av = {a, b};
      const float2v sq = av * av;      // v_pk_mul_f32
      const float ab = a * b;
#pragma unroll
      for (int j = 0; j < 8; ++j) {
        if (q < j || q > j + 10) continue;
        const float w = G_[q - j];
        const float2v w2 = {w, w};
        s01[j] = __builtin_elementwise_fma(w2, av, s01[j]);  // v_pk_fma_f32
        s23[j] = __builtin_elementwise_fma(w2, sq, s23[j]);
        s4[j] = fmaf(w, ab, s4[j]);
      }
    }

#pragma unroll
    for (int j = 0; j < 8; ++j) {
      rbA2[yb + j][c] = s01[j];        // ds_write_b64, lanes->cols: clean
      rbB2[yb + j][c] = s23[j];        // ds_write_b64: clean
      rbC[yb + j][c] = s4[j];          // ds_write_b32: clean
    }
  }
  __syncthreads();

  // ---- Pass 2: HORIZONTAL conv (packed f32) + SSIM map; 256 items exact --
  float lsum = 0.f;
  {
    const int m = tid & 15;          // col group 0..15
    const int y = tid >> 4;          // output row 0..15
    const int cb = m << 2;           // window cols cb..cb+13 (outputs cb..cb+3)

    float2v fa[14], fb[14];
#pragma unroll
    for (int k = 0; k < 14; ++k) {
      fa[k] = rbA2[y][cb + k];         // ds_read_b64 (measured clean)
      fb[k] = rbB2[y][cb + k];
    }
    float cv[16];
#pragma unroll
    for (int h = 0; h < 4; ++h) {
      *reinterpret_cast<float4*>(&cv[4 * h]) =
          *reinterpret_cast<const float4*>(&rbC[y][cb + 4 * h]);
    }

    float2v accA[4], accB[4];
    float sC[4];
#pragma unroll
    for (int j = 0; j < 4; ++j) {
      float2v a = {0, 0}, b = {0, 0};
      float c = 0.f;
#pragma unroll
      for (int k = 0; k < KK; ++k) {
        const float2v w2 = {G_[k], G_[k]};
        a = __builtin_elementwise_fma(w2, fa[j + k], a);
        b = __builtin_elementwise_fma(w2, fb[j + k], b);
        c = fmaf(G_[k], cv[j + k], c);
      }
      accA[j] = a; accB[j] = b; sC[j] = c;
    }

    const float C1 = 1.0e-4f;
    const float C2 = 9.0e-4f;
#pragma unroll
    for (int j = 0; j < 4; ++j) {
      const float mu_x = accA[j].x;
      const float mu_y = accA[j].y;
      const float2v sv = __builtin_elementwise_fma(-accA[j], accA[j], accB[j]);
      const float sxy = sC[j] - mu_x * mu_y;
      const float num = (2.f * mu_x * mu_y + C1) * (2.f * sxy + C2);
      const float den = (mu_x * mu_x + mu_y * mu_y + C1) *
                        (fmaf(sv.x, sv.x, fmaf(sv.y, sv.y, C2)));
      lsum = fmaf(num, __builtin_amdgcn_rcpf(den), lsum);
    }
  }

  // ---- Block reduction -> partial[bid] ----
#pragma unroll
  for (int off = 32; off > 0; off >>= 1) lsum += __shfl_xor(lsum, off, 64);
  if ((tid & 63) == 0) wsums[tid >> 6] = lsum;
  __syncthreads();
  if (tid == 0)
    partial[bid] = (wsums[0] + wsums[1]) + (wsums[2] + wsums[3]);
}

__global__ __launch_bounds__(1024) void ssim_reduce_kernel(
    const float* __restrict__ partial, float* __restrict__ out) {
  float s = 0.f;
  for (int i = threadIdx.x; i < NBLOCKS; i += 1024) s += partial[i];
#pragma unroll
  for (int off = 32; off > 0; off >>= 1) s += __shfl_xor(s, off, 64);
  __shared__ float ws[16];
  if ((threadIdx.x & 63) == 0) ws[threadIdx.x >> 6] = s;
  __syncthreads();
  if (threadIdx.x == 0) {
    float t = 0.f;
#pragma unroll
    for (int i = 0; i < 16; ++i) t += ws[i];
    out[0] = t * (1.0f / (float)TOTAL_ELEMS);
  }
}

extern "C" void kernel_launch(void* const* d_in, const int* in_sizes, int n_in,
                              void* d_out, int out_size, void* d_ws,
                              size_t ws_size, hipStream_t stream) {
  const float* pred = (const float*)d_in[0];
  const float* targ = (const float*)d_in[1];
  float* out = (float*)d_out;
  float* partial = (float*)d_ws;

  ssim_tile_kernel<<<NBLOCKS, NTHREADS, 0, stream>>>(pred, targ, partial);
  ssim_reduce_kernel<<<1, 1024, 0, stream>>>(partial, out);
}